// Round 1
// baseline (11790.086 us; speedup 1.0000x reference)
//
#include <hip/hip_runtime.h>

typedef unsigned short u16;
typedef unsigned int u32;
typedef __attribute__((ext_vector_type(8))) short short8;   // 8 x bf16 (4 VGPRs)
typedef __attribute__((ext_vector_type(4))) float f32x4;

#define BATCH 64
#define SEQ   512
#define ISZ   512
#define HSZ   1024
#define CMB   1536   // ISZ + HSZ
#define G4    4096   // 4 * HSZ

// ---------- helpers ----------
__device__ inline u16 f2bf(float f) {
  u32 u = __float_as_uint(f);
  u32 r = (u + 0x7fffu + ((u >> 16) & 1u)) >> 16;   // RNE; inputs finite
  return (u16)r;
}
__device__ inline float bf2f(u16 u) { return __uint_as_float(((u32)u) << 16); }
__device__ inline float sigm(float x) { return 1.f / (1.f + __expf(-x)); }
__device__ inline float tanh_(float x) { return 1.f - 2.f / (1.f + __expf(2.f * x)); }

// ---------- prep: fuse + transpose gate weights to bf16, K-major ----------
// Wp[n][k] = Wg[k][n], n = g*1024 + col, layout [4096][1536] bf16
__global__ void pack_w(const float* __restrict__ W0, const float* __restrict__ W1,
                       const float* __restrict__ W2, const float* __restrict__ W3,
                       u16* __restrict__ Wp) {
  __shared__ float tile[32][33];
  const int bid = blockIdx.x;
  const int g = bid / 1536;            // 1536 = 48 ktiles * 32 ntiles
  const int r = bid - g * 1536;
  const int kt = r >> 5, nt = r & 31;
  const float* Wg = g == 0 ? W0 : g == 1 ? W1 : g == 2 ? W2 : W3;
  const int tx = threadIdx.x & 31, ty = threadIdx.x >> 5;
#pragma unroll
  for (int i = 0; i < 4; ++i) {
    int kl = ty + i * 8;
    tile[kl][tx] = Wg[(size_t)(kt * 32 + kl) * 1024 + nt * 32 + tx];
  }
  __syncthreads();
#pragma unroll
  for (int i = 0; i < 4; ++i) {
    int nl = ty + i * 8;
    int n = g * 1024 + nt * 32 + nl;
    Wp[(size_t)n * 1536 + kt * 32 + tx] = f2bf(tile[tx][nl]);
  }
}

// ---------- prep: x [B][S][I] f32 -> xb [S][B][I] bf16 ----------
__global__ void pack_x(const float* __restrict__ x, u16* __restrict__ xb) {
  const int id = blockIdx.x * 256 + threadIdx.x;   // 2,097,152 total
  const int k8 = id & 63;
  const int row = (id >> 6) & 63;
  const int t = id >> 12;
  const float* src = x + ((size_t)(row * SEQ + t) << 9) + k8 * 8;
  float4 a = *(const float4*)src;
  float4 b = *(const float4*)(src + 4);
  uint4 v;
  v.x = (u32)f2bf(a.x) | ((u32)f2bf(a.y) << 16);
  v.y = (u32)f2bf(a.z) | ((u32)f2bf(a.w) << 16);
  v.z = (u32)f2bf(b.x) | ((u32)f2bf(b.y) << 16);
  v.w = (u32)f2bf(b.z) | ((u32)f2bf(b.w) << 16);
  *(uint4*)(xb + ((size_t)(t * BATCH + row) << 9) + k8 * 8) = v;
}

// ---------- barrier state reset (ws not re-poisoned between replays) ----------
__global__ void bar_init(u32* bar) { bar[0] = 0u; bar[1] = 0u; }

// cumulative-count grid barrier: arrival counts are generation-ordered because a
// block can only arrive at gen g+1 after gen g's count completed.
__device__ inline void gbar(u32* cnt, u32* gen, u32 target) {
  __syncthreads();                       // drains each wave's stores (vmcnt) to L2
  if (threadIdx.x == 0) {
    __threadfence();                     // agent release: buffer_wbl2 (cross-XCD publish)
    u32 old = __hip_atomic_fetch_add(cnt, 1u, __ATOMIC_RELAXED, __HIP_MEMORY_SCOPE_AGENT);
    if (old == target * 256u - 1u) {
      __hip_atomic_store(gen, target, __ATOMIC_RELEASE, __HIP_MEMORY_SCOPE_AGENT);
    } else {
      while (__hip_atomic_load(gen, __ATOMIC_RELAXED, __HIP_MEMORY_SCOPE_AGENT) < target)
        __builtin_amdgcn_s_sleep(1);
    }
    __threadfence();                     // agent acquire: buffer_inv (see fresh h)
  }
  __syncthreads();
}

// ---------- main persistent kernel ----------
// grid 256 x 256 threads. Block b owns h columns [4b, 4b+4) -> gate cols
// {g*1024 + 4b + jj}. W-slice (16 cols x 1536 K, bf16) lives in LDS, XOR-swizzled.
// Wave m computes rows [16m,16m+16) x 16 gate cols, full K, via 16x16x32 bf16 MFMA.
__global__ void __launch_bounds__(256) lstm_main(
    const u16* __restrict__ Wp, const u16* __restrict__ xb, u16* __restrict__ hb,
    u32* bar,
    const float* __restrict__ b_i, const float* __restrict__ b_f,
    const float* __restrict__ b_c, const float* __restrict__ b_o,
    const float* __restrict__ fcw, const float* __restrict__ fcb,
    float* __restrict__ out) {
  __shared__ u16 Wl[24576];   // 16 rows x 3072 B, XOR-swizzled by (row&7)<<4

  const int tid = threadIdx.x;
  const int bid = blockIdx.x;
  const int j0 = bid << 2;              // first h column owned
  const int wid = tid >> 6;             // M-tile (wave) index
  const int lane = tid & 63;
  const int l15 = lane & 15;
  const int kgrp = lane >> 4;

  // --- load W slice into LDS (once) ---
  {
    const int c = tid & 15;                     // LDS col 0..15 (gate-major: g*4+jj)
    const int g = c >> 2, jj = c & 3;
    const size_t nrow = (size_t)(g * 1024 + j0 + jj) * 1536;
    const int c0 = tid >> 4;
#pragma unroll
    for (int i = 0; i < 12; ++i) {
      int chunk = c0 + i * 16;                  // 192 x 16B chunks per row
      int byteoff = c * 3072 + chunk * 16;
      int sw = byteoff ^ ((c & 7) << 4);
      *(float4*)((char*)Wl + sw) = *(const float4*)(Wp + nrow + chunk * 8);
    }
  }
  // zero h buffer 0 (this block's 256-element share)
  hb[(bid << 8) + tid] = 0;

  // per-lane biases (valid where l15<4; jjl = l15&3 ok for all)
  const int jjl = l15 & 3;
  const float bi_r = b_i[j0 + jjl], bf_r = b_f[j0 + jjl];
  const float bc_r = b_c[j0 + jjl], bo_r = b_o[j0 + jjl];

  f32x4 cst = {0.f, 0.f, 0.f, 0.f};   // cell state, rows (kgrp*4+r)+16*wid, col j0+jjl
  u32 target = 1;
  gbar(bar, bar + 1, target++);       // h0 zeroing visible everywhere

  const int arow = wid * 16 + l15;    // A-fragment row
  const int wbyte0 = l15 * 3072 + kgrp * 16;
  const int wsw = (l15 & 7) << 4;
  const char* wbase = (const char*)Wl;

  for (int t = 0; t < SEQ; ++t) {
    const u16* hin = hb + ((t & 1) << 16);
    u16* hout = hb + (((t + 1) & 1) << 16);
    const u16* xrow = xb + ((size_t)((t << 6) + arow) << 9) + kgrp * 8;
    const u16* hrow = hin + arow * 1024 + kgrp * 8;

    f32x4 acc0 = {0.f, 0.f, 0.f, 0.f}, acc1 = {0.f, 0.f, 0.f, 0.f};
    // x part: global k-steps 0..15
#pragma unroll
    for (int ks = 0; ks < 16; ks += 2) {
      short8 a0 = *(const short8*)(xrow + ks * 32);
      short8 b0 = *(const short8*)(wbase + ((wbyte0 + ks * 64) ^ wsw));
      acc0 = __builtin_amdgcn_mfma_f32_16x16x32_bf16(a0, b0, acc0, 0, 0, 0);
      short8 a1 = *(const short8*)(xrow + ks * 32 + 32);
      short8 b1 = *(const short8*)(wbase + ((wbyte0 + ks * 64 + 64) ^ wsw));
      acc1 = __builtin_amdgcn_mfma_f32_16x16x32_bf16(a1, b1, acc1, 0, 0, 0);
    }
    // h part: global k-steps 16..47 (W byte offset +1024)
#pragma unroll
    for (int ks = 0; ks < 32; ks += 2) {
      short8 a0 = *(const short8*)(hrow + ks * 32);
      short8 b0 = *(const short8*)(wbase + ((wbyte0 + 1024 + ks * 64) ^ wsw));
      acc0 = __builtin_amdgcn_mfma_f32_16x16x32_bf16(a0, b0, acc0, 0, 0, 0);
      short8 a1 = *(const short8*)(hrow + ks * 32 + 32);
      short8 b1 = *(const short8*)(wbase + ((wbyte0 + 1024 + ks * 64 + 64) ^ wsw));
      acc1 = __builtin_amdgcn_mfma_f32_16x16x32_bf16(a1, b1, acc1, 0, 0, 0);
    }
    f32x4 v = acc0 + acc1;

    // gather i,f,g,o (cols jj, jj+4, jj+8, jj+12) and update state
#pragma unroll
    for (int r = 0; r < 4; ++r) {
      float xv = v[r];
      float fv = __shfl_xor(xv, 4);
      float gv = __shfl_xor(xv, 8);
      float ov = __shfl_xor(xv, 12);
      if (l15 < 4) {
        float ip = sigm(xv + bi_r);
        float fp = sigm(fv + bf_r);
        float gp = tanh_(gv + bc_r);
        float op = sigm(ov + bo_r);
        float cn = fp * cst[r] + ip * gp;
        cst[r] = cn;
        float h = op * tanh_(cn);
        hout[(wid * 16 + (kgrp << 2) + r) * 1024 + j0 + jjl] = f2bf(h);
      }
    }
    gbar(bar, bar + 1, target++);
  }

  // ---- epilogue: out = h_T @ fc_w^T + fc_b; final h is hb[0] ----
  {
    const int oc_i = tid >> 6;
    if (oc_i < 2) {
      const int row = tid & 63;
      const int oc = (bid << 1) + oc_i;
      const u16* hrowp = hb + row * 1024;
      const float* wr = fcw + (size_t)oc * 1024;
      float s = fcb[oc];
#pragma unroll 4
      for (int k = 0; k < 1024; k += 8) {
        ushort4 h0 = *(const ushort4*)(hrowp + k);
        ushort4 h1 = *(const ushort4*)(hrowp + k + 4);
        float4 w0 = *(const float4*)(wr + k);
        float4 w1 = *(const float4*)(wr + k + 4);
        s += bf2f(h0.x) * w0.x + bf2f(h0.y) * w0.y + bf2f(h0.z) * w0.z + bf2f(h0.w) * w0.w +
             bf2f(h1.x) * w1.x + bf2f(h1.y) * w1.y + bf2f(h1.z) * w1.z + bf2f(h1.w) * w1.w;
      }
      out[(size_t)row * 512 + oc] = s;
    }
  }
}

// ---------- launch ----------
extern "C" void kernel_launch(void* const* d_in, const int* in_sizes, int n_in,
                              void* d_out, int out_size, void* d_ws, size_t ws_size,
                              hipStream_t stream) {
  const float* x  = (const float*)d_in[0];
  const float* W0 = (const float*)d_in[1];
  const float* W1 = (const float*)d_in[2];
  const float* W2 = (const float*)d_in[3];
  const float* W3 = (const float*)d_in[4];
  const float* bi = (const float*)d_in[5];
  const float* bf = (const float*)d_in[6];
  const float* bc = (const float*)d_in[7];
  const float* bo = (const float*)d_in[8];
  const float* fcw = (const float*)d_in[9];
  const float* fcb = (const float*)d_in[10];
  float* out = (float*)d_out;

  char* ws = (char*)d_ws;
  u16* Wp = (u16*)ws;                                   // 12,582,912 B
  u16* xb = (u16*)(ws + 12582912);                      // 33,554,432 B
  u16* hb = (u16*)(ws + 12582912 + 33554432);           //    262,144 B
  u32* bar = (u32*)(ws + 12582912 + 33554432 + 262144); //        256 B

  pack_w<<<dim3(6144), dim3(256), 0, stream>>>(W0, W1, W2, W3, Wp);
  pack_x<<<dim3(8192), dim3(256), 0, stream>>>(x, xb);
  bar_init<<<dim3(1), dim3(1), 0, stream>>>(bar);
  lstm_main<<<dim3(256), dim3(256), 0, stream>>>(Wp, xb, hb, bar,
                                                 bi, bf, bc, bo, fcw, fcb, out);
}

// Round 2
// 6675.408 us; speedup vs baseline: 1.7662x; 1.7662x over previous
//
#include <hip/hip_runtime.h>

typedef unsigned short u16;
typedef unsigned int u32;
typedef unsigned long long u64;
typedef __attribute__((ext_vector_type(8))) short short8;   // 8 x bf16
typedef __attribute__((ext_vector_type(4))) float f32x4;

#define SEQ 512
#define NB  128   // blocks
#define NT  128   // threads (2 waves)

// ws layout (bytes)
#define OFF_XB    0ull          // 32 MB : xb [512][64][512] bf16
#define OFF_WHP   33554432ull   //  8 MB : Whp [128][2][32][64][8] bf16 (fragment order)
#define OFF_WXP   41943040ull   //  4 MB : Wxp [128][2][16][64][8] bf16
#define OFF_HB    46137344ull   // 256 KB: hb [2][64][1024] bf16
#define OFF_FLAGS 46399488ull   // 512 B : flags[128] u32

// ---------- helpers ----------
__device__ inline u16 f2bf(float f) {
  u32 u = __float_as_uint(f);
  u32 r = (u + 0x7fffu + ((u >> 16) & 1u)) >> 16;   // RNE
  return (u16)r;
}
__device__ inline float bf2f(u16 u) { return __uint_as_float(((u32)u) << 16); }
__device__ inline float sigm(float x) { return 1.f / (1.f + __expf(-x)); }
__device__ inline float tanh_(float x) { return 1.f - 2.f / (1.f + __expf(2.f * x)); }

// system-scope (MALL-coherent, L1/L2-bypassing) accessors
__device__ inline short8 load_h8(const u16* p) {
  union { u64 q[2]; short8 v; } u;
  u.q[0] = __hip_atomic_load((const u64*)p,       __ATOMIC_RELAXED, __HIP_MEMORY_SCOPE_SYSTEM);
  u.q[1] = __hip_atomic_load((const u64*)(p + 4), __ATOMIC_RELAXED, __HIP_MEMORY_SCOPE_SYSTEM);
  return u.v;
}
__device__ inline void store_short_sc(u16* p, u16 v) {
  asm volatile("global_store_short %0, %1, off sc0 sc1" :: "v"(p), "v"((u32)v) : "memory");
}

// ---------- prep: x [B][S][I] f32 -> xb [S][B][I] bf16 ----------
__global__ void pack_x(const float* __restrict__ x, u16* __restrict__ xb) {
  const int id = blockIdx.x * 256 + threadIdx.x;   // 2,097,152 total
  const int k8 = id & 63;
  const int row = (id >> 6) & 63;
  const int t = id >> 12;
  const float* src = x + ((size_t)(row * SEQ + t) << 9) + k8 * 8;
  float4 a = *(const float4*)src;
  float4 b = *(const float4*)(src + 4);
  uint4 v;
  v.x = (u32)f2bf(a.x) | ((u32)f2bf(a.y) << 16);
  v.y = (u32)f2bf(a.z) | ((u32)f2bf(a.w) << 16);
  v.z = (u32)f2bf(b.x) | ((u32)f2bf(b.y) << 16);
  v.w = (u32)f2bf(b.z) | ((u32)f2bf(b.w) << 16);
  *(uint4*)(xb + ((size_t)(t * 64 + row) << 9) + k8 * 8) = v;
}

// ---------- prep: gate weights f32 [1536][1024] x4 -> MFMA-fragment images ----------
// Block bid owns h-cols [bid*8, bid*8+8) -> 32 gate cols: c = nt*16+l15, g=c>>3, jj=c&7.
// Fragment (bid,nt,ks,lane): 8 bf16 = W_g[k0+j][bid*8+jj], k0 = ks*32 + (lane>>4)*8.
__global__ void pack_frag(const float* __restrict__ W0, const float* __restrict__ W1,
                          const float* __restrict__ W2, const float* __restrict__ W3,
                          u16* __restrict__ Whp, u16* __restrict__ Wxp) {
  int id = blockIdx.x * 256 + threadIdx.x;   // 786,432 total
  int bid = id / 6144;
  int r = id - bid * 6144;
  int nt = r / 3072; r -= nt * 3072;
  int ks = r >> 6;            // 0..47 (0..15 x-part, 16..47 h-part)
  int lane = r & 63;
  int kgrp = lane >> 4, l15 = lane & 15;
  int c = nt * 16 + l15, g = c >> 3, jj = c & 7;
  int hcol = bid * 8 + jj;
  const float* Wg = g == 0 ? W0 : g == 1 ? W1 : g == 2 ? W2 : W3;
  int k0 = (ks < 16 ? ks * 32 : 512 + (ks - 16) * 32) + kgrp * 8;
  u16 tmp[8];
#pragma unroll
  for (int j = 0; j < 8; ++j) tmp[j] = f2bf(Wg[(size_t)(k0 + j) * 1024 + hcol]);
  u16* dst = (ks < 16)
      ? Wxp + ((size_t)(bid * 2 + nt) * 16 + ks) * 512 + lane * 8
      : Whp + ((size_t)(bid * 2 + nt) * 32 + (ks - 16)) * 512 + lane * 8;
  *(uint4*)dst = *(uint4*)tmp;
}

// ---------- main persistent kernel ----------
// 128 blocks x 128 threads (2 waves). Block owns 8 h-cols (32 gate cols = 2 MFMA
// N-tiles). Wave w computes rows [w*32, w*32+32) (2 M-tiles). W_h (K=1024) in LDS,
// lane-ordered fragments (zero bank conflicts). h exchange: system-scope via MALL.
__global__ void __launch_bounds__(NT) lstm_main(
    const u16* __restrict__ Whp, const u16* __restrict__ Wxp,
    const u16* __restrict__ xb, u16* __restrict__ hb, u32* __restrict__ flags,
    const float* __restrict__ b_i, const float* __restrict__ b_f,
    const float* __restrict__ b_c, const float* __restrict__ b_o,
    const float* __restrict__ fcw, const float* __restrict__ fcb,
    float* __restrict__ out) {
  __shared__ u16 Wl[32768];   // 64 KB: [nt 2][ks 32][lane 64][8]

  const int tid = threadIdx.x;
  const int bid = blockIdx.x;
  const int wid = tid >> 6;
  const int lane = tid & 63;
  const int l15 = lane & 15;
  const int kgrp = lane >> 4;
  const int jj = l15 & 7;

  // stage W_h fragment image -> LDS (linear copy, one-time)
  {
    const u16* src = Whp + (size_t)bid * 32768;
#pragma unroll 4
    for (int it = 0; it < 32; ++it) {
      int e = (it * NT + tid) * 8;
      *(uint4*)&Wl[e] = *(const uint4*)&src[e];
    }
  }
  __syncthreads();

  const float bi_r = b_i[bid * 8 + jj], bf_r = b_f[bid * 8 + jj];
  const float bc_r = b_c[bid * 8 + jj], bo_r = b_o[bid * 8 + jj];

  const int row0 = wid * 32 + l15;   // mt=0 rows
  const int row1 = row0 + 16;        // mt=1 rows

  f32x4 c0 = {0.f, 0.f, 0.f, 0.f}, c1 = {0.f, 0.f, 0.f, 0.f};
  const char* WlB = (const char*)Wl;

#define MFMA(a, b, c_) __builtin_amdgcn_mfma_f32_16x16x32_bf16(a, b, c_, 0, 0, 0)
#define LOADG(B0, B1, g) \
  _Pragma("unroll") for (int k8 = 0; k8 < 8; ++k8) { \
    B0[k8] = load_h8(h0 + ((g) * 8 + k8) * 32); \
    B1[k8] = load_h8(h1 + ((g) * 8 + k8) * 32); }
#define CONSG(B0, B1, g) \
  _Pragma("unroll") for (int k8 = 0; k8 < 8; ++k8) { \
    short8 wb0 = *(const short8*)(WlB + ((((g) * 8 + k8)) * 64 + lane) * 16); \
    short8 wb1 = *(const short8*)(WlB + (((32 + (g) * 8 + k8)) * 64 + lane) * 16); \
    a00 = MFMA(B0[k8], wb0, a00); a01 = MFMA(B0[k8], wb1, a01); \
    a10 = MFMA(B1[k8], wb0, a10); a11 = MFMA(B1[k8], wb1, a11); }

  for (int t = 0; t < SEQ; ++t) {
    // ---- x-part (x_t): no dependency on h_t, overlaps other blocks' tail ----
    f32x4 a00 = {0,0,0,0}, a01 = {0,0,0,0}, a10 = {0,0,0,0}, a11 = {0,0,0,0};
    {
      const u16* x0 = xb + (((size_t)t * 64 + row0) << 9) + kgrp * 8;
      const u16* x1 = xb + (((size_t)t * 64 + row1) << 9) + kgrp * 8;
      const u16* wx = Wxp + (size_t)bid * 16384 + lane * 8;
#pragma unroll
      for (int ks = 0; ks < 16; ++ks) {
        short8 xa0 = *(const short8*)(x0 + ks * 32);
        short8 xa1 = *(const short8*)(x1 + ks * 32);
        short8 wb0 = *(const short8*)(wx + ks * 512);
        short8 wb1 = *(const short8*)(wx + 8192 + ks * 512);
        a00 = MFMA(xa0, wb0, a00); a01 = MFMA(xa0, wb1, a01);
        a10 = MFMA(xa1, wb0, a10); a11 = MFMA(xa1, wb1, a11);
      }
    }
    // ---- wait until all blocks published h_t ----
    {
      const u64* fq = (const u64*)flags + lane;   // covers flags[2*lane, 2*lane+1]
      const u32 tt = (u32)t;
      while (true) {
        u64 v = __hip_atomic_load(fq, __ATOMIC_RELAXED, __HIP_MEMORY_SCOPE_SYSTEM);
        if (__all(((u32)v >= tt) && ((u32)(v >> 32) >= tt))) break;
      }
      asm volatile("" ::: "memory");
    }
    // ---- h-part: K=1024 from hb[t&1], double-buffered groups of 8 k-steps ----
    {
      const u16* h0 = hb + ((t & 1) << 16) + row0 * 1024 + kgrp * 8;
      const u16* h1 = hb + ((t & 1) << 16) + row1 * 1024 + kgrp * 8;
      short8 pa0[8], pa1[8], pb0[8], pb1[8];
      LOADG(pa0, pa1, 0);
      LOADG(pb0, pb1, 1);
      CONSG(pa0, pa1, 0);
      LOADG(pa0, pa1, 2);
      CONSG(pb0, pb1, 1);
      LOADG(pb0, pb1, 3);
      CONSG(pa0, pa1, 2);
      CONSG(pb0, pb1, 3);
    }
    // ---- gates, cell state, publish h_{t+1} ----
    {
      u16* hout = hb + (((t + 1) & 1) << 16);
#pragma unroll
      for (int mt = 0; mt < 2; ++mt) {
        f32x4 iv = (mt == 0) ? a00 : a10;
        f32x4 gv = (mt == 0) ? a01 : a11;
#pragma unroll
        for (int r = 0; r < 4; ++r) {
          float vi = iv[r];
          float vf = __shfl_xor(vi, 8);
          float vg = gv[r];
          float vo = __shfl_xor(vg, 8);
          float ip = sigm(vi + bi_r);
          float fp = sigm(vf + bf_r);
          float gp = tanh_(vg + bc_r);
          float op = sigm(vo + bo_r);
          float cprev = (mt == 0) ? c0[r] : c1[r];
          float cn = fp * cprev + ip * gp;
          if (mt == 0) c0[r] = cn; else c1[r] = cn;
          float hval = op * tanh_(cn);
          if (l15 < 8)
            store_short_sc(hout + (wid * 32 + mt * 16 + kgrp * 4 + r) * 1024 + bid * 8 + jj,
                           f2bf(hval));
        }
      }
    }
    __syncthreads();   // drains vmcnt per wave: all h stores acked at MALL
    if (tid == 0)
      __hip_atomic_store(flags + bid, (u32)(t + 1), __ATOMIC_RELAXED, __HIP_MEMORY_SCOPE_SYSTEM);
  }

  // ---- epilogue: out = h_512 @ fc_w^T + fc_b (h_512 = hb buf0) ----
  {
    const u64* fq = (const u64*)flags + lane;
    while (true) {
      u64 v = __hip_atomic_load(fq, __ATOMIC_RELAXED, __HIP_MEMORY_SCOPE_SYSTEM);
      if (__all(((u32)v >= 512u) && ((u32)(v >> 32) >= 512u))) break;
    }
    asm volatile("" ::: "memory");
  }
  {
    const int row = tid & 63;
    const int cb = bid * 4 + (tid >> 6) * 2;
    const u16* hrow = hb + row * 1024;
    const float* w0p = fcw + (size_t)cb * 1024;
    const float* w1p = w0p + 1024;
    float s0 = fcb[cb], s1 = fcb[cb + 1];
#pragma unroll 4
    for (int k = 0; k < 1024; k += 4) {
      u64 hv = __hip_atomic_load((const u64*)(hrow + k), __ATOMIC_RELAXED, __HIP_MEMORY_SCOPE_SYSTEM);
      float h0 = bf2f((u16)hv), h1 = bf2f((u16)(hv >> 16));
      float h2 = bf2f((u16)(hv >> 32)), h3 = bf2f((u16)(hv >> 48));
      float4 w0 = *(const float4*)(w0p + k);
      float4 w1 = *(const float4*)(w1p + k);
      s0 += h0 * w0.x + h1 * w0.y + h2 * w0.z + h3 * w0.w;
      s1 += h0 * w1.x + h1 * w1.y + h2 * w1.z + h3 * w1.w;
    }
    out[row * 512 + cb] = s0;
    out[row * 512 + cb + 1] = s1;
  }
}

// ---------- launch ----------
extern "C" void kernel_launch(void* const* d_in, const int* in_sizes, int n_in,
                              void* d_out, int out_size, void* d_ws, size_t ws_size,
                              hipStream_t stream) {
  const float* x  = (const float*)d_in[0];
  const float* W0 = (const float*)d_in[1];
  const float* W1 = (const float*)d_in[2];
  const float* W2 = (const float*)d_in[3];
  const float* W3 = (const float*)d_in[4];
  const float* bi = (const float*)d_in[5];
  const float* bf = (const float*)d_in[6];
  const float* bc = (const float*)d_in[7];
  const float* bo = (const float*)d_in[8];
  const float* fcw = (const float*)d_in[9];
  const float* fcb = (const float*)d_in[10];
  float* out = (float*)d_out;

  char* ws = (char*)d_ws;
  u16* xbp   = (u16*)(ws + OFF_XB);
  u16* Whp   = (u16*)(ws + OFF_WHP);
  u16* Wxp   = (u16*)(ws + OFF_WXP);
  u16* hbp   = (u16*)(ws + OFF_HB);
  u32* flags = (u32*)(ws + OFF_FLAGS);

  pack_x<<<dim3(8192), dim3(256), 0, stream>>>(x, xbp);
  pack_frag<<<dim3(3072), dim3(256), 0, stream>>>(W0, W1, W2, W3, Whp, Wxp);
  hipMemsetAsync(hbp, 0, 131072, stream);   // h_0 = 0 (buffer 0)
  hipMemsetAsync(flags, 0, 512, stream);    // flags = 0  ("h_0 published")
  lstm_main<<<dim3(NB), dim3(NT), 0, stream>>>(Whp, Wxp, xbp, hbp, flags,
                                               bi, bf, bc, bo, fcw, fcb, out);
}

// Round 3
// 5412.523 us; speedup vs baseline: 2.1783x; 1.2333x over previous
//
#include <hip/hip_runtime.h>

typedef unsigned short u16;
typedef unsigned int u32;
typedef unsigned long long u64;
typedef __attribute__((ext_vector_type(8))) short short8;   // 8 x bf16
typedef __attribute__((ext_vector_type(4))) float f32x4;

#define SEQ 512
#define NB  128   // blocks
#define NT  128   // threads (2 waves)

// ws layout (bytes)
#define OFF_XB   0ull          // 32 MB : xbF [512][4 mt][16 ks][64 lane][8] bf16
#define OFF_WHP  33554432ull   //  8 MB : Whp [128][2 nt][32 ks][64 lane][8] bf16
#define OFF_WXP  41943040ull   //  4 MB : Wxp [128][2 nt][16 ks][64 lane][8] bf16
#define OFF_HB   46137344ull   // 256 KB: hbF [2][4 mt][32 ks][64 lane][8] bf16
#define OFF_CNT  46399488ull   // 512 B : arrival counter (u32)

// ---------- helpers ----------
__device__ inline u16 f2bf(float f) {
  u32 u = __float_as_uint(f);
  u32 r = (u + 0x7fffu + ((u >> 16) & 1u)) >> 16;   // RNE
  return (u16)r;
}
__device__ inline float bf2f(u16 u) { return __uint_as_float(((u32)u) << 16); }
__device__ inline float sigm(float x) { return 1.f / (1.f + __expf(-x)); }
__device__ inline float tanh_(float x) { return 1.f - 2.f / (1.f + __expf(2.f * x)); }

// system-scope (MALL-coherent, L1/L2-bypassing) accessors; lanes read
// consecutive addresses -> coalesced 512B bursts
__device__ inline short8 load_h8(const u16* p) {
  union { u64 q[2]; short8 v; } u;
  u.q[0] = __hip_atomic_load((const u64*)p,       __ATOMIC_RELAXED, __HIP_MEMORY_SCOPE_SYSTEM);
  u.q[1] = __hip_atomic_load((const u64*)(p + 4), __ATOMIC_RELAXED, __HIP_MEMORY_SCOPE_SYSTEM);
  return u.v;
}
__device__ inline void store_short_sc(u16* p, u16 v) {
  asm volatile("global_store_short %0, %1, off sc0 sc1" :: "v"(p), "v"((u32)v) : "memory");
}

// ---------- prep: x [B][S][I] f32 -> xbF fragment layout bf16 ----------
// elem (t,row,k) -> xbF + t*32768 + ((mt*16+ks)*64 + lane)*8 + j
//   mt=row>>4, ks=k>>5, lane=((k>>3)&3)*16 + (row&15), j=k&7
__global__ void pack_x(const float* __restrict__ x, u16* __restrict__ xb) {
  const int id = blockIdx.x * 256 + threadIdx.x;   // 2,097,152 total
  const int k8 = id & 63;            // k>>3
  const int row = (id >> 6) & 63;
  const int t = id >> 12;
  const float* src = x + ((size_t)(row * SEQ + t) << 9) + k8 * 8;
  float4 a = *(const float4*)src;
  float4 b = *(const float4*)(src + 4);
  uint4 v;
  v.x = (u32)f2bf(a.x) | ((u32)f2bf(a.y) << 16);
  v.y = (u32)f2bf(a.z) | ((u32)f2bf(a.w) << 16);
  v.z = (u32)f2bf(b.x) | ((u32)f2bf(b.y) << 16);
  v.w = (u32)f2bf(b.z) | ((u32)f2bf(b.w) << 16);
  const int mt = row >> 4, ks = k8 >> 2;
  const int lane = (k8 & 3) * 16 + (row & 15);
  *(uint4*)(xb + (size_t)t * 32768 + ((mt * 16 + ks) * 64 + lane) * 8) = v;
}

// ---------- prep: gate weights f32 [1536][1024] x4 -> MFMA B-fragment images ----------
__global__ void pack_frag(const float* __restrict__ W0, const float* __restrict__ W1,
                          const float* __restrict__ W2, const float* __restrict__ W3,
                          u16* __restrict__ Whp, u16* __restrict__ Wxp) {
  int id = blockIdx.x * 256 + threadIdx.x;   // 786,432 total
  int bid = id / 6144;
  int r = id - bid * 6144;
  int nt = r / 3072; r -= nt * 3072;
  int ks = r >> 6;            // 0..47 (0..15 x-part, 16..47 h-part)
  int lane = r & 63;
  int kgrp = lane >> 4, l15 = lane & 15;
  int c = nt * 16 + l15, g = c >> 3, jj = c & 7;
  int hcol = bid * 8 + jj;
  const float* Wg = g == 0 ? W0 : g == 1 ? W1 : g == 2 ? W2 : W3;
  int k0 = (ks < 16 ? ks * 32 : 512 + (ks - 16) * 32) + kgrp * 8;
  u16 tmp[8];
#pragma unroll
  for (int j = 0; j < 8; ++j) tmp[j] = f2bf(Wg[(size_t)(k0 + j) * 1024 + hcol]);
  u16* dst = (ks < 16)
      ? Wxp + ((size_t)(bid * 2 + nt) * 16 + ks) * 512 + lane * 8
      : Whp + ((size_t)(bid * 2 + nt) * 32 + (ks - 16)) * 512 + lane * 8;
  *(uint4*)dst = *(uint4*)tmp;
}

// ---------- main persistent kernel ----------
// 128 blocks x 128 threads (2 waves). Block owns 8 h-cols (32 gate cols).
// Wave w: rows [w*32, w*32+32) (mt = 2w, 2w+1). W_h in LDS (fragment order,
// conflict-free ds_read_b128). h exchange via MALL in A-fragment layout
// (coalesced bursts). Sync: single cumulative counter, wave0 polls.
__global__ void __launch_bounds__(NT) lstm_main(
    const u16* __restrict__ Whp, const u16* __restrict__ Wxp,
    const u16* __restrict__ xb, u16* __restrict__ hb, u32* __restrict__ cnt,
    const float* __restrict__ b_i, const float* __restrict__ b_f,
    const float* __restrict__ b_c, const float* __restrict__ b_o,
    const float* __restrict__ fcw, const float* __restrict__ fcb,
    float* __restrict__ out) {
  __shared__ u16 Wl[32768];   // 64 KB: [nt 2][ks 32][lane 64][8]

  const int tid = threadIdx.x;
  const int bid = blockIdx.x;
  const int wid = tid >> 6;
  const int lane = tid & 63;
  const int l15 = lane & 15;
  const int kgrp = lane >> 4;
  const int jj = l15 & 7;

  // stage W_h fragment image -> LDS (linear copy, one-time)
  {
    const u16* src = Whp + (size_t)bid * 32768;
#pragma unroll 4
    for (int it = 0; it < 32; ++it) {
      int e = (it * NT + tid) * 8;
      *(uint4*)&Wl[e] = *(const uint4*)&src[e];
    }
  }
  __syncthreads();

  const float bi_r = b_i[bid * 8 + jj], bf_r = b_f[bid * 8 + jj];
  const float bc_r = b_c[bid * 8 + jj], bo_r = b_o[bid * 8 + jj];

  f32x4 c0 = {0.f, 0.f, 0.f, 0.f}, c1 = {0.f, 0.f, 0.f, 0.f};
  const char* WlB = (const char*)Wl;

  // h store base (fragment layout, buffer-relative elems):
  // ((($wid*2+mt)*32 + (bid>>2))*64 + (bid&3)*16 + kgrp*4 + r)*8 + jj
  const int hst_base = (((wid * 2) * 32 + (bid >> 2)) * 64 + (bid & 3) * 16 + kgrp * 4) * 8 + jj;

#define MFMA(a, b, c_) __builtin_amdgcn_mfma_f32_16x16x32_bf16(a, b, c_, 0, 0, 0)
#define LOADG(B0, B1, g) \
  _Pragma("unroll") for (int k8 = 0; k8 < 8; ++k8) { \
    B0[k8] = load_h8(h0 + ((g) * 8 + k8) * 512); \
    B1[k8] = load_h8(h1 + ((g) * 8 + k8) * 512); }
#define CONSG(B0, B1, g) \
  _Pragma("unroll") for (int k8 = 0; k8 < 8; ++k8) { \
    short8 wb0 = *(const short8*)(WlB + ((((g) * 8 + k8)) * 64 + lane) * 16); \
    short8 wb1 = *(const short8*)(WlB + (((32 + (g) * 8 + k8)) * 64 + lane) * 16); \
    a00 = MFMA(B0[k8], wb0, a00); a01 = MFMA(B0[k8], wb1, a01); \
    a10 = MFMA(B1[k8], wb0, a10); a11 = MFMA(B1[k8], wb1, a11); }

  for (int t = 0; t < SEQ; ++t) {
    // ---- x-part (x_t): independent of h_t, overlaps other blocks' tail ----
    f32x4 a00 = {0,0,0,0}, a01 = {0,0,0,0}, a10 = {0,0,0,0}, a11 = {0,0,0,0};
    {
      const u16* x0 = xb + (size_t)t * 32768 + (wid * 2) * 8192 + lane * 8;
      const u16* x1 = x0 + 8192;
      const u16* wx = Wxp + (size_t)bid * 16384 + lane * 8;
#pragma unroll
      for (int ks = 0; ks < 16; ++ks) {
        short8 xa0 = *(const short8*)(x0 + ks * 512);
        short8 xa1 = *(const short8*)(x1 + ks * 512);
        short8 wb0 = *(const short8*)(wx + ks * 512);
        short8 wb1 = *(const short8*)(wx + 8192 + ks * 512);
        a00 = MFMA(xa0, wb0, a00); a01 = MFMA(xa0, wb1, a01);
        a10 = MFMA(xa1, wb0, a10); a11 = MFMA(xa1, wb1, a11);
      }
    }
    // ---- wait until all blocks published h_t (single-line poll, wave0 only) ----
    if (t > 0) {
      if (wid == 0) {
        const u32 tgt = (u32)t * (u32)NB;
        while (__hip_atomic_load(cnt, __ATOMIC_RELAXED, __HIP_MEMORY_SCOPE_SYSTEM) < tgt)
          __builtin_amdgcn_s_sleep(1);
      }
      __syncthreads();
      asm volatile("" ::: "memory");
    }
    // ---- h-part: K=1024 from hbF[t&1], double-buffered groups of 8 ks ----
    {
      const u16* hbuf = hb + ((t & 1) << 16);
      const u16* h0 = hbuf + (wid * 2) * 16384 + lane * 8;
      const u16* h1 = h0 + 16384;
      short8 pa0[8], pa1[8], pb0[8], pb1[8];
      LOADG(pa0, pa1, 0);
      LOADG(pb0, pb1, 1);
      CONSG(pa0, pa1, 0);
      LOADG(pa0, pa1, 2);
      CONSG(pb0, pb1, 1);
      LOADG(pb0, pb1, 3);
      CONSG(pa0, pa1, 2);
      CONSG(pb0, pb1, 3);
    }
    // ---- gates, cell state, publish h_{t+1} (fragment layout) ----
    {
      u16* hout = hb + (((t + 1) & 1) << 16);
#pragma unroll
      for (int mt = 0; mt < 2; ++mt) {
        f32x4 iv = (mt == 0) ? a00 : a10;
        f32x4 gv = (mt == 0) ? a01 : a11;
#pragma unroll
        for (int r = 0; r < 4; ++r) {
          float vi = iv[r];
          float vf = __shfl_xor(vi, 8);
          float vg = gv[r];
          float vo = __shfl_xor(vg, 8);
          float ip = sigm(vi + bi_r);
          float fp = sigm(vf + bf_r);
          float gp = tanh_(vg + bc_r);
          float op = sigm(vo + bo_r);
          float cprev = (mt == 0) ? c0[r] : c1[r];
          float cn = fp * cprev + ip * gp;
          if (mt == 0) c0[r] = cn; else c1[r] = cn;
          float hval = op * tanh_(cn);
          if (l15 < 8)
            store_short_sc(hout + hst_base + mt * 16384 + r * 8, f2bf(hval));
        }
      }
    }
    __syncthreads();   // each wave drains vmcnt: h stores acked at MALL
    if (tid == 0)
      __hip_atomic_fetch_add(cnt, 1u, __ATOMIC_RELAXED, __HIP_MEMORY_SCOPE_SYSTEM);
  }

  // ---- epilogue: out = h_512 @ fc_w^T + fc_b (h_512 = hbF buf0) ----
  if (wid == 0) {
    while (__hip_atomic_load(cnt, __ATOMIC_RELAXED, __HIP_MEMORY_SCOPE_SYSTEM) < (u32)SEQ * (u32)NB)
      __builtin_amdgcn_s_sleep(1);
  }
  __syncthreads();
  asm volatile("" ::: "memory");
  {
    const int row = tid & 63;
    const int cb = bid * 4 + (tid >> 6) * 2;
    const float* w0p = fcw + (size_t)cb * 1024;
    const float* w1p = w0p + 1024;
    float s0 = fcb[cb], s1 = fcb[cb + 1];
    const int rbase = (row >> 4) * 32 * 512 + (row & 15) * 8;
#pragma unroll 4
    for (int kb = 0; kb < 128; ++kb) {   // k = kb*8 + j
      const u16* p = hb + rbase + (kb >> 2) * 512 + (kb & 3) * 128;
      u64 q0 = __hip_atomic_load((const u64*)p,       __ATOMIC_RELAXED, __HIP_MEMORY_SCOPE_SYSTEM);
      u64 q1 = __hip_atomic_load((const u64*)(p + 4), __ATOMIC_RELAXED, __HIP_MEMORY_SCOPE_SYSTEM);
      const float* w0 = w0p + kb * 8;
      const float* w1 = w1p + kb * 8;
      float h0 = bf2f((u16)q0), h1 = bf2f((u16)(q0 >> 16));
      float h2 = bf2f((u16)(q0 >> 32)), h3 = bf2f((u16)(q0 >> 48));
      float h4 = bf2f((u16)q1), h5 = bf2f((u16)(q1 >> 16));
      float h6 = bf2f((u16)(q1 >> 32)), h7 = bf2f((u16)(q1 >> 48));
      s0 += h0 * w0[0] + h1 * w0[1] + h2 * w0[2] + h3 * w0[3] +
            h4 * w0[4] + h5 * w0[5] + h6 * w0[6] + h7 * w0[7];
      s1 += h0 * w1[0] + h1 * w1[1] + h2 * w1[2] + h3 * w1[3] +
            h4 * w1[4] + h5 * w1[5] + h6 * w1[6] + h7 * w1[7];
    }
    out[row * 512 + cb] = s0;
    out[row * 512 + cb + 1] = s1;
  }
}

// ---------- launch ----------
extern "C" void kernel_launch(void* const* d_in, const int* in_sizes, int n_in,
                              void* d_out, int out_size, void* d_ws, size_t ws_size,
                              hipStream_t stream) {
  const float* x  = (const float*)d_in[0];
  const float* W0 = (const float*)d_in[1];
  const float* W1 = (const float*)d_in[2];
  const float* W2 = (const float*)d_in[3];
  const float* W3 = (const float*)d_in[4];
  const float* bi = (const float*)d_in[5];
  const float* bf = (const float*)d_in[6];
  const float* bc = (const float*)d_in[7];
  const float* bo = (const float*)d_in[8];
  const float* fcw = (const float*)d_in[9];
  const float* fcb = (const float*)d_in[10];
  float* out = (float*)d_out;

  char* ws = (char*)d_ws;
  u16* xbp = (u16*)(ws + OFF_XB);
  u16* Whp = (u16*)(ws + OFF_WHP);
  u16* Wxp = (u16*)(ws + OFF_WXP);
  u16* hbp = (u16*)(ws + OFF_HB);
  u32* cnt = (u32*)(ws + OFF_CNT);

  pack_x<<<dim3(8192), dim3(256), 0, stream>>>(x, xbp);
  pack_frag<<<dim3(3072), dim3(256), 0, stream>>>(W0, W1, W2, W3, Whp, Wxp);
  hipMemsetAsync(hbp, 0, 131072, stream);   // h_0 = 0 (buffer 0)
  hipMemsetAsync(cnt, 0, 512, stream);      // arrival counter = 0
  lstm_main<<<dim3(NB), dim3(NT), 0, stream>>>(Whp, Wxp, xbp, hbp, cnt,
                                               bi, bf, bc, bo, fcw, fcb, out);
}

// Round 4
// 4017.508 us; speedup vs baseline: 2.9347x; 1.3472x over previous
//
#include <hip/hip_runtime.h>

typedef unsigned short u16;
typedef unsigned int u32;
typedef unsigned long long u64;
typedef __attribute__((ext_vector_type(8))) short short8;   // 8 x bf16
typedef __attribute__((ext_vector_type(4))) float f32x4;

#define SEQ 512
#define NBLK 128   // 2 groups x 64 col-blocks
#define NT   128   // 2 waves

// ws layout (bytes)
#define OFF_XB   0ull          // 32 MB : xbF [512][4 mt][16 ks][64 lane][8] bf16
#define OFF_WHP  33554432ull   //  8 MB : Whp [64 cb][4 nt][32 ks][64 lane][8] bf16
#define OFF_WXP  41943040ull   //  4 MB : Wxp [64 cb][4 nt][16 ks][64 lane][8] bf16
#define OFF_HB   46137344ull   // 256 KB: hbF [2 par][2 g][2 mt][32 ks][64 lane][8] bf16
#define OFF_FLG  46399488ull   //   8 KB: flags [2 g][64 cb] u32, 64B stride

// ---------- helpers ----------
__device__ inline u16 f2bf(float f) {
  u32 u = __float_as_uint(f);
  u32 r = (u + 0x7fffu + ((u >> 16) & 1u)) >> 16;   // RNE
  return (u16)r;
}
__device__ inline float bf2f(u16 u) { return __uint_as_float(((u32)u) << 16); }
__device__ inline float sigm(float x) { return 1.f / (1.f + __expf(-x)); }
__device__ inline float tanh_(float x) { return 1.f - 2.f / (1.f + __expf(2.f * x)); }

// system-scope (MALL-coherent) accessors
__device__ inline short8 load_h8(const u16* p) {
  union { u64 q[2]; short8 v; } u;
  u.q[0] = __hip_atomic_load((const u64*)p,       __ATOMIC_RELAXED, __HIP_MEMORY_SCOPE_SYSTEM);
  u.q[1] = __hip_atomic_load((const u64*)(p + 4), __ATOMIC_RELAXED, __HIP_MEMORY_SCOPE_SYSTEM);
  return u.v;
}
__device__ inline void store_short_sc(u16* p, u16 v) {
  asm volatile("global_store_short %0, %1, off sc0 sc1" :: "v"(p), "v"((u32)v) : "memory");
}
__device__ inline void store_u32_sc(u32* p, u32 v) {
  asm volatile("global_store_dword %0, %1, off sc0 sc1" :: "v"(p), "v"(v) : "memory");
}

// ---------- prep: x [B][S][I] f32 -> xbF fragment layout bf16 ----------
// elem (t,row,k) -> xbF + t*32768 + ((mt*16+ks)*64 + lane)*8 + j
//   mt=row>>4, ks=k>>5, lane=((k>>3)&3)*16 + (row&15), j=k&7
__global__ void pack_x(const float* __restrict__ x, u16* __restrict__ xb) {
  const int id = blockIdx.x * 256 + threadIdx.x;   // 2,097,152 total
  const int k8 = id & 63;
  const int row = (id >> 6) & 63;
  const int t = id >> 12;
  const float* src = x + ((size_t)(row * SEQ + t) << 9) + k8 * 8;
  float4 a = *(const float4*)src;
  float4 b = *(const float4*)(src + 4);
  uint4 v;
  v.x = (u32)f2bf(a.x) | ((u32)f2bf(a.y) << 16);
  v.y = (u32)f2bf(a.z) | ((u32)f2bf(a.w) << 16);
  v.z = (u32)f2bf(b.x) | ((u32)f2bf(b.y) << 16);
  v.w = (u32)f2bf(b.z) | ((u32)f2bf(b.w) << 16);
  const int mt = row >> 4, ks = k8 >> 2;
  const int lane = (k8 & 3) * 16 + (row & 15);
  *(uint4*)(xb + (size_t)t * 32768 + ((mt * 16 + ks) * 64 + lane) * 8) = v;
}

// ---------- prep: gate weights -> B-fragment images ----------
// col-block cb owns h-cols [cb*16, cb*16+16); nt = gate (0=i,1=f,2=g,3=o);
// B-frag (cb,nt,ks,lane): col=l15 -> hcol cb*16+l15, k = base(ks) + kgrp*8 + j
__global__ void pack_frag(const float* __restrict__ W0, const float* __restrict__ W1,
                          const float* __restrict__ W2, const float* __restrict__ W3,
                          u16* __restrict__ Whp, u16* __restrict__ Wxp) {
  int id = blockIdx.x * 256 + threadIdx.x;   // 786,432 total
  int cb = id / 12288;
  int r = id - cb * 12288;
  int nt = r / 3072; r -= nt * 3072;
  int ks = r >> 6;            // 0..47 (0..15 x-part, 16..47 h-part)
  int lane = r & 63;
  int kgrp = lane >> 4, l15 = lane & 15;
  int hcol = cb * 16 + l15;
  const float* Wg = nt == 0 ? W0 : nt == 1 ? W1 : nt == 2 ? W2 : W3;
  int k0 = (ks < 16 ? ks * 32 : 512 + (ks - 16) * 32) + kgrp * 8;
  u16 tmp[8];
#pragma unroll
  for (int j = 0; j < 8; ++j) tmp[j] = f2bf(Wg[(size_t)(k0 + j) * 1024 + hcol]);
  u16* dst = (ks < 16)
      ? Wxp + (size_t)cb * 32768 + ((nt * 16 + ks) * 64 + lane) * 8
      : Whp + (size_t)cb * 65536 + ((nt * 32 + (ks - 16)) * 64 + lane) * 8;
  *(uint4*)dst = *(uint4*)tmp;
}

// ---------- main persistent kernel ----------
// 128 blocks = 2 row-groups (32 batch rows each) x 64 col-blocks (16 h-cols).
// 2 waves/block: wave = mt (16 rows). W_h in LDS (128 KB, fragment order).
// W_x streamed from L2 during x-phase (off critical path). h exchange via MALL
// in A-fragment layout. Sync: per-block flag lines, lane-parallel polling.
__global__ void __launch_bounds__(NT) lstm_main(
    const u16* __restrict__ Whp, const u16* __restrict__ Wxp,
    const u16* __restrict__ xb, u16* __restrict__ hb, u32* __restrict__ flags,
    const float* __restrict__ b_i, const float* __restrict__ b_f,
    const float* __restrict__ b_c, const float* __restrict__ b_o,
    const float* __restrict__ fcw, const float* __restrict__ fcb,
    float* __restrict__ out) {
  __shared__ u16 Wl[65536];   // 128 KB: [nt 4][ks 32][lane 64][8]

  const int tid = threadIdx.x;
  const int cb = blockIdx.x & 63;
  const int g = blockIdx.x >> 6;
  const int wid = tid >> 6;
  const int lane = tid & 63;
  const int l15 = lane & 15;
  const int kgrp = lane >> 4;

  // one-time W_h LDS fill
  {
    const u16* src = Whp + (size_t)cb * 65536;
#pragma unroll 4
    for (int it = 0; it < 64; ++it) {
      int e = (it * NT + tid) * 8;
      *(uint4*)&Wl[e] = *(const uint4*)&src[e];
    }
  }
  __syncthreads();

  const float bi_r = b_i[cb * 16 + l15], bf_r = b_f[cb * 16 + l15];
  const float bc_r = b_c[cb * 16 + l15], bo_r = b_o[cb * 16 + l15];

  f32x4 cst = {0.f, 0.f, 0.f, 0.f};
  const char* WlB = (const char*)Wl;

  // h-store base (elems, parity-relative): block stores (row g*32+wid*16+kgrp*4+r,
  // hcol cb*16+l15) -> frag addr: ks'=cb>>1, kgrp2=((cb&1)<<1)|(l15>>3), j'=l15&7,
  // lane'=kgrp2*16 + kgrp*4 + r
  const int kgrp2 = ((cb & 1) << 1) | (l15 >> 3);
  const int st_base = g * 32768 + wid * 16384 + (cb >> 1) * 512 +
                      (kgrp2 * 16 + kgrp * 4) * 8 + (l15 & 7);

  const u32* fp = flags + (g << 10) + (lane << 4);   // own group's 64 flags, 1/lane
  const int mtg = g * 2 + wid;                        // global batch M-tile

#define MFMA(a, b, c_) __builtin_amdgcn_mfma_f32_16x16x32_bf16(a, b, c_, 0, 0, 0)
#define LOADH(P, grp) \
  _Pragma("unroll") for (int k8 = 0; k8 < 8; ++k8) \
    P[k8] = load_h8(hr + ((grp) * 8 + k8) * 512);
#define CONSH(P, grp) \
  _Pragma("unroll") for (int k8 = 0; k8 < 8; ++k8) { \
    int idx = (grp) * 8 + k8; \
    short8 w0 = *(const short8*)(WlB + ((0 * 32 + idx) * 64 + lane) * 16); \
    short8 w1 = *(const short8*)(WlB + ((1 * 32 + idx) * 64 + lane) * 16); \
    short8 w2 = *(const short8*)(WlB + ((2 * 32 + idx) * 64 + lane) * 16); \
    short8 w3 = *(const short8*)(WlB + ((3 * 32 + idx) * 64 + lane) * 16); \
    ac0 = MFMA(P[k8], w0, ac0); ac1 = MFMA(P[k8], w1, ac1); \
    ac2 = MFMA(P[k8], w2, ac2); ac3 = MFMA(P[k8], w3, ac3); }

  for (int t = 0; t < SEQ; ++t) {
    // ---- x-part: independent of h_t ----
    f32x4 ac0 = {0,0,0,0}, ac1 = {0,0,0,0}, ac2 = {0,0,0,0}, ac3 = {0,0,0,0};
    {
      const u16* xr = xb + (size_t)t * 32768 + mtg * 8192 + lane * 8;
      const u16* wx = Wxp + (size_t)cb * 32768 + lane * 8;
#pragma unroll 4
      for (int ks = 0; ks < 16; ++ks) {
        short8 xa = *(const short8*)(xr + ks * 512);
        short8 w0 = *(const short8*)(wx + (0 * 16 + ks) * 512);
        short8 w1 = *(const short8*)(wx + (1 * 16 + ks) * 512);
        short8 w2 = *(const short8*)(wx + (2 * 16 + ks) * 512);
        short8 w3 = *(const short8*)(wx + (3 * 16 + ks) * 512);
        ac0 = MFMA(xa, w0, ac0); ac1 = MFMA(xa, w1, ac1);
        ac2 = MFMA(xa, w2, ac2); ac3 = MFMA(xa, w3, ac3);
      }
    }
    // ---- per-wave poll: all 64 col-blocks of own group published h_t ----
    if (t > 0) {
      u32 v;
      do { v = __hip_atomic_load(fp, __ATOMIC_RELAXED, __HIP_MEMORY_SCOPE_SYSTEM); }
      while (!__all(v >= (u32)t));
      asm volatile("" ::: "memory");
    }
    // ---- h-part: K=1024, 4 groups of 8 ks, 3-deep load pipeline ----
    {
      const u16* hr = hb + ((t & 1) * 65536) + g * 32768 + wid * 16384 + lane * 8;
      short8 pa[8], pb[8], pc[8];
      LOADH(pa, 0); LOADH(pb, 1); LOADH(pc, 2);
      CONSH(pa, 0);
      LOADH(pa, 3);
      CONSH(pb, 1); CONSH(pc, 2); CONSH(pa, 3);
    }
    // ---- gates (all in-lane), cell state, publish h_{t+1} ----
    {
      u16* hst = hb + (((t + 1) & 1) * 65536) + st_base;
#pragma unroll
      for (int r = 0; r < 4; ++r) {
        float ip = sigm(ac0[r] + bi_r);
        float fpv = sigm(ac1[r] + bf_r);
        float gp = tanh_(ac2[r] + bc_r);
        float op = sigm(ac3[r] + bo_r);
        float cn = fpv * cst[r] + ip * gp;
        cst[r] = cn;
        store_short_sc(hst + r * 8, f2bf(op * tanh_(cn)));
      }
    }
    asm volatile("s_waitcnt vmcnt(0)" ::: "memory");
    __syncthreads();   // both waves' stores drained & acked at MALL
    if (tid == 0) store_u32_sc(flags + (g << 10) + (cb << 4), (u32)(t + 1));
  }

  // ---- epilogue: out rows [g*32, g*32+32), cols [cb*8, cb*8+8) ----
  {
    u32 v;
    do { v = __hip_atomic_load(fp, __ATOMIC_RELAXED, __HIP_MEMORY_SCOPE_SYSTEM); }
    while (!__all(v >= (u32)SEQ));
    asm volatile("" ::: "memory");
  }
  {
    const int rl = tid & 31;            // row within group
    const int cp = tid >> 5;            // 0..3 -> col pair
    const int mt = rl >> 4, l15r = rl & 15;
    const int c0 = cb * 8 + cp * 2;
    const u16* hbase = hb + g * 32768 + mt * 16384 + l15r * 8;   // parity 0
    const float* w0p = fcw + (size_t)c0 * 1024;
    const float* w1p = w0p + 1024;
    float s0 = fcb[c0], s1 = fcb[c0 + 1];
#pragma unroll 4
    for (int kb = 0; kb < 128; ++kb) {   // k = kb*8 + j
      const u16* p = hbase + (kb >> 2) * 512 + (kb & 3) * 128;
      u64 q0 = __hip_atomic_load((const u64*)p,       __ATOMIC_RELAXED, __HIP_MEMORY_SCOPE_SYSTEM);
      u64 q1 = __hip_atomic_load((const u64*)(p + 4), __ATOMIC_RELAXED, __HIP_MEMORY_SCOPE_SYSTEM);
      const float* w0 = w0p + kb * 8;
      const float* w1 = w1p + kb * 8;
      float h0 = bf2f((u16)q0), h1 = bf2f((u16)(q0 >> 16));
      float h2 = bf2f((u16)(q0 >> 32)), h3 = bf2f((u16)(q0 >> 48));
      float h4 = bf2f((u16)q1), h5 = bf2f((u16)(q1 >> 16));
      float h6 = bf2f((u16)(q1 >> 32)), h7 = bf2f((u16)(q1 >> 48));
      s0 += h0 * w0[0] + h1 * w0[1] + h2 * w0[2] + h3 * w0[3] +
            h4 * w0[4] + h5 * w0[5] + h6 * w0[6] + h7 * w0[7];
      s1 += h0 * w1[0] + h1 * w1[1] + h2 * w1[2] + h3 * w1[3] +
            h4 * w1[4] + h5 * w1[5] + h6 * w1[6] + h7 * w1[7];
    }
    out[(size_t)(g * 32 + rl) * 512 + c0] = s0;
    out[(size_t)(g * 32 + rl) * 512 + c0 + 1] = s1;
  }
}

// ---------- launch ----------
extern "C" void kernel_launch(void* const* d_in, const int* in_sizes, int n_in,
                              void* d_out, int out_size, void* d_ws, size_t ws_size,
                              hipStream_t stream) {
  const float* x  = (const float*)d_in[0];
  const float* W0 = (const float*)d_in[1];
  const float* W1 = (const float*)d_in[2];
  const float* W2 = (const float*)d_in[3];
  const float* W3 = (const float*)d_in[4];
  const float* bi = (const float*)d_in[5];
  const float* bf = (const float*)d_in[6];
  const float* bc = (const float*)d_in[7];
  const float* bo = (const float*)d_in[8];
  const float* fcw = (const float*)d_in[9];
  const float* fcb = (const float*)d_in[10];
  float* out = (float*)d_out;

  char* ws = (char*)d_ws;
  u16* xbp = (u16*)(ws + OFF_XB);
  u16* Whp = (u16*)(ws + OFF_WHP);
  u16* Wxp = (u16*)(ws + OFF_WXP);
  u16* hbp = (u16*)(ws + OFF_HB);
  u32* flg = (u32*)(ws + OFF_FLG);

  pack_x<<<dim3(8192), dim3(256), 0, stream>>>(x, xbp);
  pack_frag<<<dim3(3072), dim3(256), 0, stream>>>(W0, W1, W2, W3, Whp, Wxp);
  hipMemsetAsync(hbp, 0, 131072, stream);   // h_0 = 0 (parity-0 buffer)
  hipMemsetAsync(flg, 0, 8192, stream);     // flags = 0
  lstm_main<<<dim3(NBLK), dim3(NT), 0, stream>>>(Whp, Wxp, xbp, hbp, flg,
                                                 bi, bf, bc, bo, fcw, fcb, out);
}

// Round 5
// 3855.999 us; speedup vs baseline: 3.0576x; 1.0419x over previous
//
#include <hip/hip_runtime.h>

typedef unsigned short u16;
typedef unsigned int u32;
typedef unsigned long long u64;
typedef __attribute__((ext_vector_type(8))) short short8;   // 8 x bf16
typedef __attribute__((ext_vector_type(4))) float f32x4;

#define SEQ 512
#define NW   128   // workers: 2 groups x 64 col-blocks
#define NCP  4     // max copiers per XCD
#define NGRID 160  // workers + copier pool
#define NT   128   // threads (2 waves)

// ws layout (bytes)
#define OFF_XB   0ull          // 32 MB : xbF [512][4 mt][16 ks][64 lane][8] bf16
#define OFF_WHP  33554432ull   //  8 MB : Whp [64 cb][4 nt][32 ks][64 lane][8] bf16
                               //         (reused after LDS fill as per-XCD staging:
                               //          stg[xcd] = OFF_WHP + xcd*256KB, [2 par][128KB])
#define OFF_WXP  41943040ull   //  4 MB : Wxp [64 cb][4 nt][16 ks][64 lane][8] bf16
#define OFF_HB   46137344ull   // 256 KB: hbF [2 par][2 g][2 mt][32 ks][64 lane][8] bf16
#define OFF_FLG  46399488ull   //   8 KB: flags [128 wid] u32, 64B stride
#define OFF_CTL  46407680ull   //   2 KB: xcnt[8]@+x*64 | lcnt[8]@512+x*64 | gready@1024 | widcnt@1088

// ---------- helpers ----------
__device__ inline u16 f2bf(float f) {
  u32 u = __float_as_uint(f);
  u32 r = (u + 0x7fffu + ((u >> 16) & 1u)) >> 16;   // RNE
  return (u16)r;
}
__device__ inline float bf2f(u16 u) { return __uint_as_float(((u32)u) << 16); }
__device__ inline float sigm(float x) { return 1.f / (1.f + __expf(-x)); }
__device__ inline float tanh_(float x) { return 1.f - 2.f / (1.f + __expf(2.f * x)); }

#define SLD(p) __hip_atomic_load((p), __ATOMIC_RELAXED, __HIP_MEMORY_SCOPE_SYSTEM)
#define ALD(p) __hip_atomic_load((p), __ATOMIC_RELAXED, __HIP_MEMORY_SCOPE_AGENT)

// agent-scope (sc0: L1-bypass, L2-hit) fragment load from same-XCD staging
__device__ inline short8 load_h8a(const u16* p) {
  union { u64 q[2]; short8 v; } u;
  u.q[0] = ALD((const u64*)p);
  u.q[1] = ALD((const u64*)(p + 4));
  return u.v;
}
__device__ inline void store_short_sc(u16* p, u16 v) {
  asm volatile("global_store_short %0, %1, off sc0 sc1" :: "v"(p), "v"((u32)v) : "memory");
}
__device__ inline void store_u32_sc(u32* p, u32 v) {
  asm volatile("global_store_dword %0, %1, off sc0 sc1" :: "v"(p), "v"(v) : "memory");
}

// ---------- prep: x [B][S][I] f32 -> xbF fragment layout bf16 ----------
__global__ void pack_x(const float* __restrict__ x, u16* __restrict__ xb) {
  const int id = blockIdx.x * 256 + threadIdx.x;   // 2,097,152 total
  const int k8 = id & 63;
  const int row = (id >> 6) & 63;
  const int t = id >> 12;
  const float* src = x + ((size_t)(row * SEQ + t) << 9) + k8 * 8;
  float4 a = *(const float4*)src;
  float4 b = *(const float4*)(src + 4);
  uint4 v;
  v.x = (u32)f2bf(a.x) | ((u32)f2bf(a.y) << 16);
  v.y = (u32)f2bf(a.z) | ((u32)f2bf(a.w) << 16);
  v.z = (u32)f2bf(b.x) | ((u32)f2bf(b.y) << 16);
  v.w = (u32)f2bf(b.z) | ((u32)f2bf(b.w) << 16);
  const int mt = row >> 4, ks = k8 >> 2;
  const int lane = (k8 & 3) * 16 + (row & 15);
  *(uint4*)(xb + (size_t)t * 32768 + ((mt * 16 + ks) * 64 + lane) * 8) = v;
}

// ---------- prep: gate weights -> B-fragment images ----------
__global__ void pack_frag(const float* __restrict__ W0, const float* __restrict__ W1,
                          const float* __restrict__ W2, const float* __restrict__ W3,
                          u16* __restrict__ Whp, u16* __restrict__ Wxp) {
  int id = blockIdx.x * 256 + threadIdx.x;   // 786,432 total
  int cb = id / 12288;
  int r = id - cb * 12288;
  int nt = r / 3072; r -= nt * 3072;
  int ks = r >> 6;
  int lane = r & 63;
  int kgrp = lane >> 4, l15 = lane & 15;
  int hcol = cb * 16 + l15;
  const float* Wg = nt == 0 ? W0 : nt == 1 ? W1 : nt == 2 ? W2 : W3;
  int k0 = (ks < 16 ? ks * 32 : 512 + (ks - 16) * 32) + kgrp * 8;
  u16 tmp[8];
#pragma unroll
  for (int j = 0; j < 8; ++j) tmp[j] = f2bf(Wg[(size_t)(k0 + j) * 1024 + hcol]);
  u16* dst = (ks < 16)
      ? Wxp + (size_t)cb * 32768 + ((nt * 16 + ks) * 64 + lane) * 8
      : Whp + (size_t)cb * 65536 + ((nt * 32 + (ks - 16)) * 64 + lane) * 8;
  *(uint4*)dst = *(uint4*)tmp;
}

// ---------- copier: per-XCD relay MALL -> local L2 staging ----------
__device__ void copier_loop(int slot, int cx, const u16* hb, u16* stg,
                            const u32* flags, u32* lcnt) {
  const int tid = threadIdx.x;
  const int per = (8192 + cx - 1) / cx;        // 16B units of one 128KB parity image
  const int u0 = slot * per;
  const int u1 = min(8192, u0 + per);
  for (int t = 1; t <= SEQ; ++t) {
    if (tid < 64) {                            // wave0 polls all 128 worker flags
      const u32* f1 = flags + tid * 16;
      const u32* f2 = flags + (tid + 64) * 16;
      u32 a, b;
      do { a = SLD(f1); b = SLD(f2); } while (__any(a < (u32)t || b < (u32)t));
    }
    __syncthreads();
    asm volatile("" ::: "memory");
    const int p = t & 1;
    const u64* sq = (const u64*)(hb + p * 65536);
    u64* dq = (u64*)(stg + p * 65536);
    int u = u0 + tid;
    for (; u + 3 * NT < u1; u += 4 * NT) {
      u64 v0a = SLD(sq + 2 * u);              u64 v0b = SLD(sq + 2 * u + 1);
      u64 v1a = SLD(sq + 2 * (u + NT));       u64 v1b = SLD(sq + 2 * (u + NT) + 1);
      u64 v2a = SLD(sq + 2 * (u + 2 * NT));   u64 v2b = SLD(sq + 2 * (u + 2 * NT) + 1);
      u64 v3a = SLD(sq + 2 * (u + 3 * NT));   u64 v3b = SLD(sq + 2 * (u + 3 * NT) + 1);
      dq[2 * u] = v0a;              dq[2 * u + 1] = v0b;
      dq[2 * (u + NT)] = v1a;       dq[2 * (u + NT) + 1] = v1b;
      dq[2 * (u + 2 * NT)] = v2a;   dq[2 * (u + 2 * NT) + 1] = v2b;
      dq[2 * (u + 3 * NT)] = v3a;   dq[2 * (u + 3 * NT) + 1] = v3b;
    }
    for (; u < u1; u += NT) {
      u64 a = SLD(sq + 2 * u), b = SLD(sq + 2 * u + 1);
      dq[2 * u] = a; dq[2 * u + 1] = b;
    }
    asm volatile("s_waitcnt vmcnt(0)" ::: "memory");   // staging visible in local L2
    __syncthreads();
    if (tid == 0)
      __hip_atomic_fetch_add(lcnt, 1u, __ATOMIC_RELEASE, __HIP_MEMORY_SCOPE_WORKGROUP);
  }
}

// ---------- main persistent kernel ----------
__global__ void __launch_bounds__(NT) lstm_main(
    const u16* __restrict__ Whp, const u16* __restrict__ Wxp,
    const u16* __restrict__ xb, u16* __restrict__ hb, char* __restrict__ ws,
    const float* __restrict__ b_i, const float* __restrict__ b_f,
    const float* __restrict__ b_c, const float* __restrict__ b_o,
    const float* __restrict__ fcw, const float* __restrict__ fcb,
    float* __restrict__ out) {
  __shared__ u16 Wl[65536];   // 128 KB: [nt 4][ks 32][lane 64][8]
  __shared__ u32 sh_slot, sh_nx, sh_wid;

  const int tid = threadIdx.x;
  u32* flags = (u32*)(ws + OFF_FLG);
  u32* ctl = (u32*)(ws + OFF_CTL);

  u32 xcd;
  asm volatile("s_getreg_b32 %0, hwreg(HW_REG_XCC_ID, 0, 8)" : "=s"(xcd));
  xcd &= 7;
  u32* xcnt = ctl + xcd * 16;
  u32* lcnt = ctl + 128 + xcd * 16;
  u32* gready = ctl + 256;
  u32* widcnt = ctl + 272;

  // ---- election: slot on own XCD (L2 atomic), global readiness (MALL) ----
  if (tid == 0) {
    sh_slot = __hip_atomic_fetch_add(xcnt, 1u, __ATOMIC_RELAXED, __HIP_MEMORY_SCOPE_WORKGROUP);
    __hip_atomic_fetch_add(gready, 1u, __ATOMIC_RELAXED, __HIP_MEMORY_SCOPE_SYSTEM);
  }
  __syncthreads();
  if (tid == 0) {
    while (SLD(gready) < (u32)NGRID) __builtin_amdgcn_s_sleep(1);
    u32 nx = ALD(xcnt);
    sh_nx = nx;
    u32 cx = nx < NCP ? nx : NCP;
    sh_wid = (sh_slot >= cx)
        ? __hip_atomic_fetch_add(widcnt, 1u, __ATOMIC_RELAXED, __HIP_MEMORY_SCOPE_SYSTEM)
        : 0xffffffffu;
  }
  __syncthreads();
  const u32 cx = sh_nx < NCP ? sh_nx : NCP;
  u16* stg = (u16*)(ws + OFF_WHP) + (size_t)xcd * 131072;   // 256KB/XCD (2 parities)

  if (sh_wid == 0xffffffffu) {   // ---- copier role ----
    copier_loop((int)sh_slot, (int)cx, hb, stg, flags, lcnt);
    return;
  }
  const u32 wid = sh_wid;
  if (wid >= NW) return;          // surplus worker (uneven XCD distribution)
  const int cb = wid & 63;
  const int g = wid >> 6;

  const int wv = tid >> 6;        // wave id = M-tile
  const int lane = tid & 63;
  const int l15 = lane & 15;
  const int kgrp = lane >> 4;

  // one-time W_h LDS fill (completes before any copier writes stg: copiers
  // gate on flags>=1, which requires every worker to pass step 0)
  {
    const u16* src = Whp + (size_t)cb * 65536;
#pragma unroll 4
    for (int it = 0; it < 64; ++it) {
      int e = (it * NT + tid) * 8;
      *(uint4*)&Wl[e] = *(const uint4*)&src[e];
    }
  }
  __syncthreads();

  const float bi_r = b_i[cb * 16 + l15], bf_r = b_f[cb * 16 + l15];
  const float bc_r = b_c[cb * 16 + l15], bo_r = b_o[cb * 16 + l15];

  f32x4 cst = {0.f, 0.f, 0.f, 0.f};
  const char* WlB = (const char*)Wl;

  const int kgrp2 = ((cb & 1) << 1) | (l15 >> 3);
  const int st_base = g * 32768 + wv * 16384 + (cb >> 1) * 512 +
                      (kgrp2 * 16 + kgrp * 4) * 8 + (l15 & 7);

#define MFMA(a, b, c_) __builtin_amdgcn_mfma_f32_16x16x32_bf16(a, b, c_, 0, 0, 0)
#define LOADH(P, grp) \
  _Pragma("unroll") for (int k8 = 0; k8 < 8; ++k8) \
    P[k8] = load_h8a(hr + ((grp) * 8 + k8) * 512);
#define CONSH(P, grp) \
  _Pragma("unroll") for (int k8 = 0; k8 < 8; ++k8) { \
    int idx = (grp) * 8 + k8; \
    short8 w0 = *(const short8*)(WlB + ((0 * 32 + idx) * 64 + lane) * 16); \
    short8 w1 = *(const short8*)(WlB + ((1 * 32 + idx) * 64 + lane) * 16); \
    short8 w2 = *(const short8*)(WlB + ((2 * 32 + idx) * 64 + lane) * 16); \
    short8 w3 = *(const short8*)(WlB + ((3 * 32 + idx) * 64 + lane) * 16); \
    ac0 = MFMA(P[k8], w0, ac0); ac1 = MFMA(P[k8], w1, ac1); \
    ac2 = MFMA(P[k8], w2, ac2); ac3 = MFMA(P[k8], w3, ac3); }

  for (int t = 0; t < SEQ; ++t) {
    // ---- x-part: independent of h_t (issued before local poll) ----
    f32x4 ac0 = {0,0,0,0}, ac1 = {0,0,0,0}, ac2 = {0,0,0,0}, ac3 = {0,0,0,0};
    {
      const u16* xr = xb + (size_t)t * 32768 + (g * 2 + wv) * 8192 + lane * 8;
      const u16* wx = Wxp + (size_t)cb * 32768 + lane * 8;
#pragma unroll 4
      for (int ks = 0; ks < 16; ++ks) {
        short8 xa = *(const short8*)(xr + ks * 512);
        short8 w0 = *(const short8*)(wx + (0 * 16 + ks) * 512);
        short8 w1 = *(const short8*)(wx + (1 * 16 + ks) * 512);
        short8 w2 = *(const short8*)(wx + (2 * 16 + ks) * 512);
        short8 w3 = *(const short8*)(wx + (3 * 16 + ks) * 512);
        ac0 = MFMA(xa, w0, ac0); ac1 = MFMA(xa, w1, ac1);
        ac2 = MFMA(xa, w2, ac2); ac3 = MFMA(xa, w3, ac3);
      }
    }
    if (t > 0) {
      // ---- local wait: own XCD's staging holds h_t ----
      const u32 need = cx * (u32)t;
      while (ALD(lcnt) < need) {}
      asm volatile("" ::: "memory");
      // ---- h-part from local L2 staging ----
      const u16* hr = stg + ((t & 1) * 65536) + g * 32768 + wv * 16384 + lane * 8;
      short8 pa[8], pb[8], pc[8];
      LOADH(pa, 0); LOADH(pb, 1); LOADH(pc, 2);
      CONSH(pa, 0);
      LOADH(pa, 3);
      CONSH(pb, 1); CONSH(pc, 2); CONSH(pa, 3);
    }
    // ---- gates (in-lane), cell state, publish h_{t+1} to MALL ----
    {
      u16* hst = hb + (((t + 1) & 1) * 65536) + st_base;
#pragma unroll
      for (int r = 0; r < 4; ++r) {
        float ip = sigm(ac0[r] + bi_r);
        float fpv = sigm(ac1[r] + bf_r);
        float gp = tanh_(ac2[r] + bc_r);
        float op = sigm(ac3[r] + bo_r);
        float cn = fpv * cst[r] + ip * gp;
        cst[r] = cn;
        store_short_sc(hst + r * 8, f2bf(op * tanh_(cn)));
      }
    }
    asm volatile("s_waitcnt vmcnt(0)" ::: "memory");
    __syncthreads();   // both waves' h stores acked at MALL
    if (tid == 0) store_u32_sc(flags + wid * 16, (u32)(t + 1));
  }

  // ---- epilogue: wait final relay, FC from local staging (parity 0) ----
  {
    const u32 need = cx * (u32)SEQ;
    while (ALD(lcnt) < need) {}
    asm volatile("" ::: "memory");
  }
  {
    const int rl = tid & 31;
    const int cp = tid >> 5;
    const int mt = rl >> 4, l15r = rl & 15;
    const int c0 = cb * 8 + cp * 2;
    const u16* hbase = stg + g * 32768 + mt * 16384 + l15r * 8;   // parity 0
    const float* w0p = fcw + (size_t)c0 * 1024;
    const float* w1p = w0p + 1024;
    float s0 = fcb[c0], s1 = fcb[c0 + 1];
#pragma unroll 4
    for (int kb = 0; kb < 128; ++kb) {
      const u16* p = hbase + (kb >> 2) * 512 + (kb & 3) * 128;
      u64 q0 = ALD((const u64*)p);
      u64 q1 = ALD((const u64*)(p + 4));
      const float* w0 = w0p + kb * 8;
      const float* w1 = w1p + kb * 8;
      float h0 = bf2f((u16)q0), h1 = bf2f((u16)(q0 >> 16));
      float h2 = bf2f((u16)(q0 >> 32)), h3 = bf2f((u16)(q0 >> 48));
      float h4 = bf2f((u16)q1), h5 = bf2f((u16)(q1 >> 16));
      float h6 = bf2f((u16)(q1 >> 32)), h7 = bf2f((u16)(q1 >> 48));
      s0 += h0 * w0[0] + h1 * w0[1] + h2 * w0[2] + h3 * w0[3] +
            h4 * w0[4] + h5 * w0[5] + h6 * w0[6] + h7 * w0[7];
      s1 += h0 * w1[0] + h1 * w1[1] + h2 * w1[2] + h3 * w1[3] +
            h4 * w1[4] + h5 * w1[5] + h6 * w1[6] + h7 * w1[7];
    }
    out[(size_t)(g * 32 + rl) * 512 + c0] = s0;
    out[(size_t)(g * 32 + rl) * 512 + c0 + 1] = s1;
  }
}

// ---------- launch ----------
extern "C" void kernel_launch(void* const* d_in, const int* in_sizes, int n_in,
                              void* d_out, int out_size, void* d_ws, size_t ws_size,
                              hipStream_t stream) {
  const float* x  = (const float*)d_in[0];
  const float* W0 = (const float*)d_in[1];
  const float* W1 = (const float*)d_in[2];
  const float* W2 = (const float*)d_in[3];
  const float* W3 = (const float*)d_in[4];
  const float* bi = (const float*)d_in[5];
  const float* bf = (const float*)d_in[6];
  const float* bc = (const float*)d_in[7];
  const float* bo = (const float*)d_in[8];
  const float* fcw = (const float*)d_in[9];
  const float* fcb = (const float*)d_in[10];
  float* out = (float*)d_out;

  char* ws = (char*)d_ws;
  u16* xbp = (u16*)(ws + OFF_XB);
  u16* Whp = (u16*)(ws + OFF_WHP);
  u16* Wxp = (u16*)(ws + OFF_WXP);
  u16* hbp = (u16*)(ws + OFF_HB);

  pack_x<<<dim3(8192), dim3(256), 0, stream>>>(x, xbp);
  pack_frag<<<dim3(3072), dim3(256), 0, stream>>>(W0, W1, W2, W3, Whp, Wxp);
  hipMemsetAsync(ws + OFF_FLG, 0, 10240, stream);   // flags + control block
  lstm_main<<<dim3(NGRID), dim3(NT), 0, stream>>>(Whp, Wxp, xbp, hbp, ws,
                                                  bi, bf, bc, bo, fcw, fcb, out);
}